// Round 1
// baseline (1118.887 us; speedup 1.0000x reference)
//
#include <hip/hip_runtime.h>

// AGNN / GatedGCN layer for MI355X (gfx950).
// ws layout (bytes), total ~292.1 MB:
//   [0)          wt: 7 weights, bf16, transposed [n][k], 7*16384 ushort = 229376
//   [229376)     hQ (N*D f32, 25.6MB), hR, hU, hV, agg  (5 x 25.6MB)
//   [+128MB)     ehat (E*D bf16, 163.84MB)
//   [+163.84MB)  stats slots: esum/esq/nsum/nsq (32x128 f32 each, 64KB)
//   [+64KB)      sce/she/scn/shn (128 f32 each)

#define NN 50000
#define NE 640000
#define D 128

typedef unsigned int uint32;
typedef unsigned short u16;
typedef short bf16x8 __attribute__((ext_vector_type(8)));
typedef float floatx4 __attribute__((ext_vector_type(4)));

__device__ __forceinline__ u16 f2bf(float f) {
  uint32 u = __float_as_uint(f);
  u += 0x7fffu + ((u >> 16) & 1u);
  return (u16)(u >> 16);
}
__device__ __forceinline__ float bfu2f(uint32 lo16) { return __uint_as_float(lo16 << 16); }
__device__ __forceinline__ uint32 pack2(float a, float b) {
  return (uint32)f2bf(a) | ((uint32)f2bf(b) << 16);
}

// 64x128 @ 128x128 MFMA tile: Xs [64][136] bf16 row-major (m,k), Ws [128][136] bf16 (n,k).
// Wave w computes rows [16w,16w+16). acc[nt] covers cols [16nt,16nt+16).
// A-frag: lane holds A[m=lane&15][k=(lane>>4)*8+j]; B-frag: B[k][n=lane&15] same k-pattern.
// D: row=(lane>>4)*4+r, col=lane&15.  LDS stride 136 (=272B) -> 2-way bank alias (free).
__device__ __forceinline__ void mfma_tile64(const u16* __restrict__ Xs,
                                            const u16* __restrict__ Ws,
                                            floatx4 acc[8], int wave, int lane) {
  const int q = lane >> 4, l = lane & 15;
  const u16* ax = Xs + (wave * 16 + l) * 136 + q * 8;
  const u16* bx = Ws + l * 136 + q * 8;
#pragma unroll
  for (int kk = 0; kk < 4; ++kk) {
    bf16x8 a = *(const bf16x8*)(ax + kk * 32);
#pragma unroll
    for (int nt = 0; nt < 8; ++nt) {
      bf16x8 b = *(const bf16x8*)(bx + nt * 16 * 136 + kk * 32);
      acc[nt] = __builtin_amdgcn_mfma_f32_16x16x32_bf16(a, b, acc[nt], 0, 0, 0);
    }
  }
}

// K1: convert 7 weights [k][n] f32 -> transposed bf16 [n][k]
__global__ __launch_bounds__(256) void k_wconv(
    const float* __restrict__ Pw, const float* __restrict__ Qw, const float* __restrict__ Rw,
    const float* __restrict__ Uw, const float* __restrict__ Vw, const float* __restrict__ W1,
    const float* __restrict__ W2, u16* __restrict__ wt) {
  int b = blockIdx.x;
  const float* s = (b == 0) ? Pw : (b == 1) ? Qw : (b == 2) ? Rw : (b == 3) ? Uw
                 : (b == 4) ? Vw : (b == 5) ? W1 : W2;
  u16* dstp = wt + b * 16384;
  for (int idx = threadIdx.x; idx < 16384; idx += 256) {
    int k = idx >> 7, n = idx & 127;
    dstp[n * 128 + k] = f2bf(s[idx]);
  }
}

// K2: hQ/hR/hU/hV = h @ {Qw,Rw,Uw,Vw}
__global__ __launch_bounds__(256) void k_node_gemm(
    const float* __restrict__ h, const u16* __restrict__ wt, float* __restrict__ hQ,
    float* __restrict__ hR, float* __restrict__ hU, float* __restrict__ hV) {
  __shared__ u16 Xs[64 * 136];
  __shared__ u16 Ws[128 * 136];
  const int tid = threadIdx.x;
  const int wave = tid >> 6, lane = tid & 63;
  const int q = lane >> 4, l = lane & 15;
  const int row0 = blockIdx.x * 64;

#pragma unroll
  for (int it = 0; it < 8; ++it) {
    int idx = (it * 256 + tid) * 4;
    int r = idx >> 7, c = idx & 127;
    int g = row0 + r;
    float4 v = make_float4(0.f, 0.f, 0.f, 0.f);
    if (g < NN) v = *(const float4*)(h + (size_t)g * D + c);
    uint2 p;
    p.x = pack2(v.x, v.y);
    p.y = pack2(v.z, v.w);
    *(uint2*)(Xs + r * 136 + c) = p;
  }

  float* const outs[4] = {hQ, hR, hU, hV};
#pragma unroll
  for (int wi = 0; wi < 4; ++wi) {
#pragma unroll
    for (int it = 0; it < 8; ++it) {
      int idx = (it * 256 + tid) * 8;
      *(uint4*)(Ws + (idx >> 7) * 136 + (idx & 127)) =
          *(const uint4*)(wt + (wi + 1) * 16384 + idx);
    }
    __syncthreads();
    floatx4 acc[8] = {};
    mfma_tile64(Xs, Ws, acc, wave, lane);
    float* outp = outs[wi];
#pragma unroll
    for (int nt = 0; nt < 8; ++nt) {
#pragma unroll
      for (int r = 0; r < 4; ++r) {
        int m = wave * 16 + q * 4 + r;
        int g = row0 + m;
        if (g < NN) outp[(size_t)g * D + nt * 16 + l] = acc[nt][r];
      }
    }
    __syncthreads();
  }
}

// K3: ehat = e@P + hQ[src] + hR[dst]; store bf16; gate=sigmoid(ehat);
//     agg[src] += gate*hV[dst]; BN-e stats partials.
__global__ __launch_bounds__(256) void k_edge1(
    const float* __restrict__ e, const int* __restrict__ src, const int* __restrict__ dst,
    const u16* __restrict__ wt, const float* __restrict__ hQ, const float* __restrict__ hR,
    const float* __restrict__ hV, u16* __restrict__ ehat, float* __restrict__ agg,
    float* __restrict__ esum, float* __restrict__ esq) {
  __shared__ u16 Xs[64 * 136];
  __shared__ u16 Ws[128 * 136];
  __shared__ int sSrc[64], sDst[64];
  __shared__ float sSum[128], sSq[128];
  const int tid = threadIdx.x;
  const int wave = tid >> 6, lane = tid & 63;
  const int q = lane >> 4, l = lane & 15;
  const int row0 = blockIdx.x * 64;

  if (tid < 128) { sSum[tid] = 0.f; sSq[tid] = 0.f; }
  if (tid < 64) { sSrc[tid] = src[row0 + tid]; sDst[tid] = dst[row0 + tid]; }
#pragma unroll
  for (int it = 0; it < 8; ++it) {
    int idx = (it * 256 + tid) * 4;
    int r = idx >> 7, c = idx & 127;
    float4 v = *(const float4*)(e + (size_t)(row0 + r) * D + c);
    uint2 p;
    p.x = pack2(v.x, v.y);
    p.y = pack2(v.z, v.w);
    *(uint2*)(Xs + r * 136 + c) = p;
  }
#pragma unroll
  for (int it = 0; it < 8; ++it) {
    int idx = (it * 256 + tid) * 8;
    *(uint4*)(Ws + (idx >> 7) * 136 + (idx & 127)) = *(const uint4*)(wt + idx);  // Pw
  }
  __syncthreads();

  floatx4 acc[8] = {};
  mfma_tile64(Xs, Ws, acc, wave, lane);

  float cs[8] = {}, cq[8] = {};
#pragma unroll
  for (int nt = 0; nt < 8; ++nt) {
    const int n = nt * 16 + l;
#pragma unroll
    for (int r = 0; r < 4; ++r) {
      const int m = wave * 16 + q * 4 + r;
      const int s = sSrc[m], dd = sDst[m];
      float v = acc[nt][r] + hQ[(size_t)s * D + n] + hR[(size_t)dd * D + n];
      ehat[(size_t)(row0 + m) * D + n] = f2bf(v);
      float gate = 1.0f / (1.0f + __expf(-v));
      atomicAdd(&agg[(size_t)s * D + n], gate * hV[(size_t)dd * D + n]);
      cs[nt] += v;
      cq[nt] += v * v;
    }
  }
#pragma unroll
  for (int nt = 0; nt < 8; ++nt) {
    cs[nt] += __shfl_xor(cs[nt], 16);
    cs[nt] += __shfl_xor(cs[nt], 32);
    cq[nt] += __shfl_xor(cq[nt], 16);
    cq[nt] += __shfl_xor(cq[nt], 32);
    if (q == 0) {
      atomicAdd(&sSum[nt * 16 + l], cs[nt]);
      atomicAdd(&sSq[nt * 16 + l], cq[nt]);
    }
  }
  __syncthreads();
  if (tid < 128) {
    atomicAdd(&esum[(blockIdx.x & 31) * D + tid], sSum[tid]);
    atomicAdd(&esq[(blockIdx.x & 31) * D + tid], sSq[tid]);
  }
}

// K4: BN-n stats partials over x = hU + agg
__global__ __launch_bounds__(256) void k_node_stats(const float* __restrict__ hU,
                                                    const float* __restrict__ agg,
                                                    float* __restrict__ nsum,
                                                    float* __restrict__ nsq) {
  __shared__ float4 Ls[256], Lq[256];
  const int tid = threadIdx.x;
  const int row0 = blockIdx.x * 64;
  const int c4 = (tid & 31) * 4, rs = tid >> 5;
  float4 s = make_float4(0.f, 0.f, 0.f, 0.f), sq = make_float4(0.f, 0.f, 0.f, 0.f);
#pragma unroll
  for (int i = 0; i < 8; ++i) {
    int g = row0 + i * 8 + rs;
    if (g < NN) {
      float4 u = *(const float4*)(hU + (size_t)g * D + c4);
      float4 a = *(const float4*)(agg + (size_t)g * D + c4);
      float x0 = u.x + a.x, x1 = u.y + a.y, x2 = u.z + a.z, x3 = u.w + a.w;
      s.x += x0; s.y += x1; s.z += x2; s.w += x3;
      sq.x += x0 * x0; sq.y += x1 * x1; sq.z += x2 * x2; sq.w += x3 * x3;
    }
  }
  Ls[tid] = s;
  Lq[tid] = sq;
  __syncthreads();
  if (tid < 128) {
    int grp = tid >> 2, comp = tid & 3;
    float ts = 0.f, tq = 0.f;
#pragma unroll
    for (int k = 0; k < 8; ++k) {
      ts += ((const float*)&Ls[k * 32 + grp])[comp];
      tq += ((const float*)&Lq[k * 32 + grp])[comp];
    }
    atomicAdd(&nsum[(blockIdx.x & 31) * D + tid], ts);
    atomicAdd(&nsq[(blockIdx.x & 31) * D + tid], tq);
  }
}

// K5: finalize both BNs into scale/shift
__global__ __launch_bounds__(128) void k_finalize(
    const float* __restrict__ esum, const float* __restrict__ esq,
    const float* __restrict__ nsum, const float* __restrict__ nsq,
    const float* __restrict__ ge, const float* __restrict__ be, const float* __restrict__ gn,
    const float* __restrict__ bnb, float* __restrict__ sce, float* __restrict__ she,
    float* __restrict__ scn, float* __restrict__ shn) {
  const int t = threadIdx.x;
  float s = 0.f, q = 0.f;
  for (int i = 0; i < 32; ++i) { s += esum[i * D + t]; q += esq[i * D + t]; }
  float mean = s / (float)NE;
  float var = q / (float)NE - mean * mean;
  float istd = rsqrtf(var + 1e-5f);
  sce[t] = istd * ge[t];
  she[t] = be[t] - mean * istd * ge[t];
  s = 0.f; q = 0.f;
  for (int i = 0; i < 32; ++i) { s += nsum[i * D + t]; q += nsq[i * D + t]; }
  mean = s / (float)NN;
  var = q / (float)NN - mean * mean;
  istd = rsqrtf(var + 1e-5f);
  scn[t] = istd * gn[t];
  shn[t] = bnb[t] - mean * istd * gn[t];
}

// K6: e_new = e + relu(BN(ehat)@W1 + b1)@W2 + b2
__global__ __launch_bounds__(256) void k_edge2(
    const u16* __restrict__ ehat, const float* __restrict__ e, const u16* __restrict__ wt,
    const float* __restrict__ sce, const float* __restrict__ she, const float* __restrict__ b1,
    const float* __restrict__ b2, float* __restrict__ oute) {
  __shared__ u16 Ts[64 * 136];
  __shared__ u16 Ws[128 * 136];
  __shared__ float sSc[128], sSh[128], sB1[128], sB2[128];
  const int tid = threadIdx.x;
  const int wave = tid >> 6, lane = tid & 63;
  const int q = lane >> 4, l = lane & 15;
  const int row0 = blockIdx.x * 64;

  if (tid < 128) { sSc[tid] = sce[tid]; sSh[tid] = she[tid]; sB1[tid] = b1[tid]; sB2[tid] = b2[tid]; }
  __syncthreads();

#pragma unroll
  for (int it = 0; it < 4; ++it) {
    int idx = (it * 256 + tid) * 8;
    int r = idx >> 7, c = idx & 127;
    uint4 u = *(const uint4*)(ehat + (size_t)(row0 + r) * D + c);
    float f0 = bfu2f(u.x & 0xffffu) * sSc[c + 0] + sSh[c + 0];
    float f1 = bfu2f(u.x >> 16) * sSc[c + 1] + sSh[c + 1];
    float f2 = bfu2f(u.y & 0xffffu) * sSc[c + 2] + sSh[c + 2];
    float f3 = bfu2f(u.y >> 16) * sSc[c + 3] + sSh[c + 3];
    float f4 = bfu2f(u.z & 0xffffu) * sSc[c + 4] + sSh[c + 4];
    float f5 = bfu2f(u.z >> 16) * sSc[c + 5] + sSh[c + 5];
    float f6 = bfu2f(u.w & 0xffffu) * sSc[c + 6] + sSh[c + 6];
    float f7 = bfu2f(u.w >> 16) * sSc[c + 7] + sSh[c + 7];
    uint4 o;
    o.x = pack2(f0, f1); o.y = pack2(f2, f3); o.z = pack2(f4, f5); o.w = pack2(f6, f7);
    *(uint4*)(Ts + r * 136 + c) = o;
  }
#pragma unroll
  for (int it = 0; it < 8; ++it) {
    int idx = (it * 256 + tid) * 8;
    *(uint4*)(Ws + (idx >> 7) * 136 + (idx & 127)) = *(const uint4*)(wt + 5 * 16384 + idx);  // W1
  }
  __syncthreads();

  floatx4 acc[8] = {};
  mfma_tile64(Ts, Ws, acc, wave, lane);
  __syncthreads();  // all reads of Ts/Ws done before overwrite

#pragma unroll
  for (int nt = 0; nt < 8; ++nt) {
    int n = nt * 16 + l;
#pragma unroll
    for (int r = 0; r < 4; ++r) {
      int m = wave * 16 + q * 4 + r;
      float v = acc[nt][r] + sB1[n];
      Ts[m * 136 + n] = f2bf(fmaxf(v, 0.f));
    }
  }
#pragma unroll
  for (int it = 0; it < 8; ++it) {
    int idx = (it * 256 + tid) * 8;
    *(uint4*)(Ws + (idx >> 7) * 136 + (idx & 127)) = *(const uint4*)(wt + 6 * 16384 + idx);  // W2
  }
  __syncthreads();

  floatx4 acc2[8] = {};
  mfma_tile64(Ts, Ws, acc2, wave, lane);

#pragma unroll
  for (int nt = 0; nt < 8; ++nt) {
    int n = nt * 16 + l;
#pragma unroll
    for (int r = 0; r < 4; ++r) {
      int m = wave * 16 + q * 4 + r;
      size_t gi = (size_t)(row0 + m) * D + n;
      oute[gi] = e[gi] + acc2[nt][r] + sB2[n];
    }
  }
}

// K7: h_new = h + alpha * (x*scale + shift), x = hU + agg
__global__ __launch_bounds__(256) void k_node_out(
    const float* __restrict__ h, const float* __restrict__ hU, const float* __restrict__ agg,
    const float* __restrict__ scn, const float* __restrict__ shn,
    const float* __restrict__ alphap, float* __restrict__ outh) {
  size_t idx = ((size_t)blockIdx.x * 256 + threadIdx.x) * 4;
  if (idx >= (size_t)NN * D) return;
  int c = (int)(idx & 127);
  float al = alphap[0];
  float4 u = *(const float4*)(hU + idx);
  float4 a = *(const float4*)(agg + idx);
  float4 hh = *(const float4*)(h + idx);
  float4 o;
  o.x = hh.x + al * ((u.x + a.x) * scn[c + 0] + shn[c + 0]);
  o.y = hh.y + al * ((u.y + a.y) * scn[c + 1] + shn[c + 1]);
  o.z = hh.z + al * ((u.z + a.z) * scn[c + 2] + shn[c + 2]);
  o.w = hh.w + al * ((u.w + a.w) * scn[c + 3] + shn[c + 3]);
  *(float4*)(outh + idx) = o;
}

extern "C" void kernel_launch(void* const* d_in, const int* in_sizes, int n_in, void* d_out,
                              int out_size, void* d_ws, size_t ws_size, hipStream_t stream) {
  const float* h = (const float*)d_in[0];
  const float* e = (const float*)d_in[1];
  const int* ei = (const int*)d_in[2];
  const float* Pw = (const float*)d_in[3];
  const float* Qw = (const float*)d_in[4];
  const float* Rw = (const float*)d_in[5];
  const float* Uw = (const float*)d_in[6];
  const float* Vw = (const float*)d_in[7];
  const float* W1 = (const float*)d_in[8];
  const float* b1 = (const float*)d_in[9];
  const float* W2 = (const float*)d_in[10];
  const float* b2 = (const float*)d_in[11];
  const float* ge = (const float*)d_in[12];
  const float* be = (const float*)d_in[13];
  const float* gn = (const float*)d_in[14];
  const float* bnb = (const float*)d_in[15];
  const float* al = (const float*)d_in[16];

  const int* srcp = ei;
  const int* dstp = ei + NE;

  char* ws = (char*)d_ws;
  u16* wt = (u16*)(ws);
  float* hQ = (float*)(ws + 229376ull);
  float* hR = (float*)(ws + 229376ull + 1ull * 25600000ull);
  float* hU = (float*)(ws + 229376ull + 2ull * 25600000ull);
  float* hV = (float*)(ws + 229376ull + 3ull * 25600000ull);
  float* agg = (float*)(ws + 229376ull + 4ull * 25600000ull);
  u16* ehat = (u16*)(ws + 229376ull + 5ull * 25600000ull);
  char* statb = ws + 229376ull + 5ull * 25600000ull + 163840000ull;
  float* esum = (float*)(statb);
  float* esq = (float*)(statb + 16384);
  float* nsum = (float*)(statb + 32768);
  float* nsq = (float*)(statb + 49152);
  float* sce = (float*)(statb + 65536);
  float* she = (float*)(statb + 65536 + 512);
  float* scn = (float*)(statb + 65536 + 1024);
  float* shn = (float*)(statb + 65536 + 1536);

  float* outh = (float*)d_out;
  float* oute = outh + (size_t)NN * D;

  hipMemsetAsync(agg, 0, (size_t)NN * D * sizeof(float), stream);
  hipMemsetAsync(statb, 0, 65536, stream);

  k_wconv<<<7, 256, 0, stream>>>(Pw, Qw, Rw, Uw, Vw, W1, W2, wt);
  k_node_gemm<<<782, 256, 0, stream>>>(h, wt, hQ, hR, hU, hV);
  k_edge1<<<10000, 256, 0, stream>>>(e, srcp, dstp, wt, hQ, hR, hV, ehat, agg, esum, esq);
  k_node_stats<<<782, 256, 0, stream>>>(hU, agg, nsum, nsq);
  k_finalize<<<1, 128, 0, stream>>>(esum, esq, nsum, nsq, ge, be, gn, bnb, sce, she, scn, shn);
  k_edge2<<<10000, 256, 0, stream>>>(ehat, e, wt, sce, she, b1, b2, oute);
  k_node_out<<<6250, 256, 0, stream>>>(h, hU, agg, scn, shn, al, outh);
}